// Round 16
// baseline (14133.156 us; speedup 1.0000x reference)
//
#include <hip/hip_runtime.h>

// R16: query batching. G=8 queries per 1024-thread block => each fit4 load
// feeds 8 queries (global traffic /8, latency amortized). Per-query key
// arithmetic bit-identical to R15. Selection per query unchanged: 2-pass
// exact u16 radix (8 parallel histograms), bitmask collection, cv staging
// (stride-65), fp64 re-key, per-column exact top-K. Fast-math-proof.

#define NQ 16384
#define NF 8192
#define D  64
#define G  8
#define TCAP 64
#define RANK 32
#define CVS 65

typedef unsigned short u16;
typedef unsigned int u32;
typedef unsigned long long u64;

#define IDX_INVALID 0xFFFFFFFFu
#define NANF_BITS   0x7FC00000u
#define FLTMAX_BITS 0x7F7FFFFFu

__device__ __forceinline__ int f32_missing_bits(u32 b) {
    return ((b >> 23) & 0xFFu) == 0xFFu;      // NaN/inf => missing
}

// ---- prep: fit (row-major [NF,64]) -> fit4 (group-major [16][NF] float4) ----
__global__ __launch_bounds__(256) void prep_fit4(const float* __restrict__ fit,
                                                 float4* __restrict__ fit4) {
    int idx = blockIdx.x * 256 + threadIdx.x;     // 0 .. NF*16-1
    int g = idx / NF;
    int f = idx - g * NF;
    const float4* src = (const float4*)(fit + (size_t)f * D);
    fit4[(size_t)g * NF + f] = src[g];
}

__global__ __launch_bounds__(1024) void knn_r16(
        const float* __restrict__ X,
        const float* __restrict__ fit,
        const float4* __restrict__ fit4,          // may be null -> fallback
        const int* __restrict__ pk,
        float* __restrict__ out) {
    __shared__ __align__(16) unsigned char s_pool[133120];  // keys(128K) U cv(130K)
    __shared__ __align__(16) unsigned char s_pool2[16384];  // hist U masks
    __shared__ __align__(16) float s_xv[G * D];             // 2 KB
    __shared__ u64   s_xmask[G];
    __shared__ u32   s_ci[G * TCAP];                        // 2 KB
    __shared__ double s_kd[G * TCAP];                       // 4 KB
    __shared__ u32   s_sel0[G], s_below0[G], s_sel1[G];

    u16*   s_k16 = (u16*)s_pool;
    float* s_cv  = (float*)s_pool;
    u32*   s_hist = (u32*)s_pool2;
    u64*   s_blw  = (u64*)s_pool2;
    u64*   s_tie  = (u64*)(s_pool2 + 8192);

    const int tid = threadIdx.x;
    const int q0 = blockIdx.x * G;

    if (tid < G * D) {                     // waves 0..7, wave == query
        int g = tid >> 6, d = tid & 63;
        float xf = X[((size_t)q0 + g) * D + d];
        int obs = !f32_missing_bits(__float_as_uint(xf));
        s_xv[tid] = obs ? xf : 0.f;
        u64 bal = __ballot(obs != 0);
        if (d == 0) s_xmask[g] = bal;
    }
    __syncthreads();

    u32 xlo[G], xhi[G];
#pragma unroll
    for (int g = 0; g < G; ++g) {
        u64 xm = s_xmask[g];
        xlo[g] = (u32)xm; xhi[g] = (u32)(xm >> 32);
    }
    const float4* xv4 = (const float4*)s_xv;

    // ---- phase 1: keys for 8 queries per donor load ----
    for (int i = 0; i < 8; ++i) {
        int f = tid + (i << 10);
        float ssd[G]; int pres[G];
#pragma unroll
        for (int g = 0; g < G; ++g) { ssd[g] = 0.f; pres[g] = 0; }
#pragma unroll
        for (int m = 0; m < 16; ++m) {
            float4 w = (fit4 != nullptr)
                     ? fit4[(size_t)m * NF + f]
                     : ((const float4*)fit)[(size_t)f * 16 + m];
            float wv[4] = { w.x, w.y, w.z, w.w };
            u32 vm = 0;
#pragma unroll
            for (int u = 0; u < 4; ++u)
                vm |= (u32)f32_missing_bits(__float_as_uint(wv[u])) << u;
            const u32 keep = (~vm) & 0xFu;
#pragma unroll
            for (int g = 0; g < G; ++g) {
                float4 xc = xv4[g * 16 + m];
                float xw[4] = { xc.x, xc.y, xc.z, xc.w };
                u32 xn = ((m < 8 ? xlo[g] : xhi[g]) >> ((m & 7) * 4)) & 0xFu;
                u32 okn = xn & keep;
#pragma unroll
                for (int u = 0; u < 4; ++u) {
                    int ok = (int)((okn >> u) & 1u);
                    float t = ok ? wv[u] : xw[u];
                    float dm = xw[u] - t;          // = ok ? x - v : 0
                    ssd[g] = fmaf(dm, dm, ssd[g]);
                    pres[g] += ok;
                }
            }
        }
#pragma unroll
        for (int g = 0; g < G; ++g) {
            float kk = (pres[g] > 0) ? (ssd[g] / (float)pres[g])
                                     : __uint_as_float(FLTMAX_BITS);
            s_k16[g * NF + f] = (u16)(__float_as_uint(kk) >> 16);
        }
    }
    __syncthreads();

    int K = *pk;
    if (K < 1 || K > 64) {
        float kf = __int_as_float(K);
        K = (kf >= 1.f && kf <= 64.f) ? (int)kf : 5;
    }
    if (K > TCAP) K = TCAP;

    const int g2 = tid >> 7, lane2 = tid & 127;
    const u16* kp = s_k16 + g2 * NF;

    // ---- phase 2a: per-query exact rank-32 u16 threshold, 2 byte passes ----
    s_hist[tid] = 0; s_hist[tid + 1024] = 0;
    __syncthreads();
    for (int i = 0; i < 64; ++i) {
        u32 k = (u32)kp[lane2 + i * 128];
        atomicAdd(&s_hist[g2 * 256 + (k >> 8)], 1u);
    }
    __syncthreads();
    if (lane2 == 0) {
        u32 run = 0, below = 0, sel = 255;
        for (int b = 0; b < 256; ++b) {
            u32 c = s_hist[g2 * 256 + b];
            if (run + c >= (u32)RANK) { sel = (u32)b; below = run; break; }
            run += c;
        }
        s_sel0[g2] = sel; s_below0[g2] = below;
    }
    __syncthreads();
    const u32 sel0 = s_sel0[g2];
    const u32 need1 = (u32)RANK - s_below0[g2];
    __syncthreads();
    s_hist[tid] = 0; s_hist[tid + 1024] = 0;
    __syncthreads();
    for (int i = 0; i < 64; ++i) {
        u32 k = (u32)kp[lane2 + i * 128];
        if ((k >> 8) == sel0) atomicAdd(&s_hist[g2 * 256 + (k & 0xFFu)], 1u);
    }
    __syncthreads();
    if (lane2 == 0) {
        u32 run = 0, sel = 255;
        for (int b = 0; b < 256; ++b) {
            u32 c = s_hist[g2 * 256 + b];
            if (run + c >= need1) { sel = (u32)b; break; }
            run += c;
        }
        s_sel1[g2] = sel;
    }
    __syncthreads();
    const u32 thr16 = (s_sel0[g2] << 8) | s_sel1[g2];

    // ---- phase 2a': collection via bitmasks (after last hist read) ----
    {
        u64 bb = 0, tb = 0;
        for (int i = 0; i < 64; ++i) {
            u32 k = (u32)kp[lane2 + i * 128];
            bb |= (u64)(k < thr16)  << i;
            tb |= (u64)(k == thr16) << i;
        }
        __syncthreads();                    // hist region dead; reuse as masks
        s_blw[g2 * 128 + lane2] = bb;
        s_tie[g2 * 128 + lane2] = tb;
    }
    __syncthreads();
    if (lane2 == 0) {
        int n = 0;
        for (int t = 0; t < 128 && n < TCAP; ++t) {
            u64 w = s_blw[g2 * 128 + t];
            while (w && n < TCAP) {
                int i = __ffsll((unsigned long long)w) - 1; w &= w - 1;
                s_ci[g2 * TCAP + n++] = (u32)(t + i * 128);
            }
        }
        u32 tf[TCAP]; int nt = 0;
        for (int t = 0; t < 128 && nt < TCAP; ++t) {
            u64 w = s_tie[g2 * 128 + t];
            while (w && nt < TCAP) {
                int i = __ffsll((unsigned long long)w) - 1; w &= w - 1;
                tf[nt++] = (u32)(t + i * 128);
            }
        }
        int cap = TCAP - n;
        if (nt <= cap) {
            for (int r = 0; r < nt; ++r) s_ci[g2 * TCAP + n++] = tf[r];
        } else {
            for (int j = 0; j < cap; ++j) {        // prefer smallest donor idx
                int bp = -1; u32 bi = IDX_INVALID;
                for (int r = 0; r < nt; ++r)
                    if (tf[r] < bi) { bi = tf[r]; bp = r; }
                tf[bp] = IDX_INVALID;
                s_ci[g2 * TCAP + n++] = bi;
            }
        }
        for (; n < TCAP; ++n) s_ci[g2 * TCAP + n] = IDX_INVALID;
    }
    __syncthreads();

    // ---- phase 2c: stage candidate rows into cv (overlays dead keys) ----
#pragma unroll
    for (int t = 0; t < 32; ++t) {
        int e = tid + t * 1024;                    // 0 .. 32767
        int d = e & 63, r = (e >> 6) & 63, g = e >> 12;
        u32 ci = s_ci[g * TCAP + r];
        float v = (ci != IDX_INVALID) ? fit[(size_t)ci * D + d]
                                      : __uint_as_float(NANF_BITS);
        s_cv[(g * 64 + r) * CVS + d] = v;
    }
    __syncthreads();

    // ---- phase 2b: exact fp64 re-key from staged rows ----
    if (tid < G * TCAP) {
        int g = tid >> 6, r = tid & 63;
        u32 ci = s_ci[g * TCAP + r];
        double kd = 1.0e300;
        if (ci != IDX_INVALID) {
            const float* cvrow = &s_cv[(g * 64 + r) * CVS];
            u64 xm = s_xmask[g];
            double ss = 0.0; int pr = 0;
            for (int j = 0; j < D; ++j) {
                float yf = cvrow[j];
                int ok = (int)((xm >> j) & 1ull)
                       & (f32_missing_bits(__float_as_uint(yf)) ^ 1);
                double dd = ok ? ((double)s_xv[g * 64 + j] - (double)yf) : 0.0;
                ss = fma(dd, dd, ss);
                pr += ok;
            }
            kd = (pr > 0) ? (ss / (double)pr) : 1.0e300;
        }
        s_kd[tid] = kd;
    }
    __syncthreads();

    // ---- phase 2d: per-(query,column) imputation ----
    if (tid < G * D) {
        int g = tid >> 6, d = tid & 63;
        u64 xm = s_xmask[g];
        int xobs = (int)((xm >> d) & 1ull);
        float res;
        if (xobs) {
            res = s_xv[g * 64 + d];
        } else {
            u64 used = 0; float sum = 0.f; int cnt = 0;
            for (int s = 0; s < K; ++s) {
                int best = -1; double bk = 0.0; u32 bi = 0;
                for (int r = 0; r < TCAP; ++r) {
                    if ((used >> r) & 1ull) continue;
                    u32 ci = s_ci[g * TCAP + r];
                    if (ci == IDX_INVALID) continue;
                    float v = s_cv[(g * 64 + r) * CVS + d];
                    if (f32_missing_bits(__float_as_uint(v))) continue;
                    double kd = s_kd[g * TCAP + r];
                    if (kd >= 1.0e300) continue;
                    if (best < 0 || kd < bk || (kd == bk && ci < bi)) {
                        best = r; bk = kd; bi = ci;
                    }
                }
                if (best < 0) break;
                used |= 1ull << best;
                sum += s_cv[(g * 64 + best) * CVS + d];
                cnt++;
            }
            if (cnt > 0) {
                res = sum / (float)cnt;
            } else {
                float cs = 0.f; int cc = 0;        // essentially-never fallback
                for (int f = 0; f < NF; ++f) {
                    float yf = fit[(size_t)f * D + d];
                    if (!f32_missing_bits(__float_as_uint(yf))) { cs += yf; cc++; }
                }
                res = cc > 0 ? cs / (float)cc : 0.f;
            }
            u32 rb = __float_as_uint(res);
            if (((rb >> 23) & 0xFFu) == 0xFFu) res = 0.f;
        }
        out[((size_t)q0 + g) * D + d] = res;
    }
}

// ---- launch ------------------------------------------------------------------
extern "C" void kernel_launch(void* const* d_in, const int* in_sizes, int n_in,
                              void* d_out, int out_size, void* d_ws, size_t ws_size,
                              hipStream_t stream) {
    const void* pX = d_in[0];
    const void* pF = (n_in > 1) ? d_in[1] : d_in[0];
    const void* pK = (n_in > 2) ? d_in[2] : d_in[0];
    for (int i = 0; i < n_in; ++i) {
        if (in_sizes[i] == NQ * D)      pX = d_in[i];
        else if (in_sizes[i] == NF * D) pF = d_in[i];
        else if (in_sizes[i] == 1)      pK = d_in[i];
    }
    const float* X   = (const float*)pX;
    const float* fit = (const float*)pF;
    const int*   pk  = (const int*)pK;
    float* out = (float*)d_out;

    const size_t need = (size_t)NF * D * sizeof(float);   // 2 MB
    if (ws_size >= need) {
        float4* fit4 = (float4*)d_ws;
        prep_fit4<<<(NF * 16) / 256, 256, 0, stream>>>(fit, fit4);
        knn_r16<<<NQ / G, 1024, 0, stream>>>(X, fit, fit4, pk, out);
    } else {
        knn_r16<<<NQ / G, 1024, 0, stream>>>(X, fit, nullptr, pk, out);
    }
}